// Round 2
// baseline (131.648 us; speedup 1.0000x reference)
//
#include <hip/hip_runtime.h>

#define LSEQ 384
#define DIM 256
#define H 32
#define ODIM 128
#define EPSV 1e-5f

// ---------------------------------------------------------------------------
// Kernel 1: LayerNorm + a = xn @ Wa^T, bT = (xn @ Wb^T)^T
// One block per row i (384 blocks, 256 threads).
// ---------------------------------------------------------------------------
__global__ __launch_bounds__(256) void ln_ab_kernel(
    const float* __restrict__ x, const float* __restrict__ gamma,
    const float* __restrict__ beta, const float* __restrict__ Wa,
    const float* __restrict__ Wb, float* __restrict__ a_g,
    float* __restrict__ bT_g) {
  const int i = blockIdx.x;
  const int tid = threadIdx.x;
  __shared__ float xn_s[DIM];
  __shared__ float psum[256];
  __shared__ float red_s[4];
  __shared__ float mu_s, rs_s;

  float xv = x[i * DIM + tid];

  // block mean
  float s = xv;
#pragma unroll
  for (int off = 32; off > 0; off >>= 1) s += __shfl_down(s, off, 64);
  const int wave = tid >> 6, lane = tid & 63;
  if (lane == 0) red_s[wave] = s;
  __syncthreads();
  if (tid == 0) mu_s = (red_s[0] + red_s[1] + red_s[2] + red_s[3]) * (1.0f / DIM);
  __syncthreads();
  const float mu = mu_s;
  const float dv = xv - mu;

  // block variance
  float s2 = dv * dv;
#pragma unroll
  for (int off = 32; off > 0; off >>= 1) s2 += __shfl_down(s2, off, 64);
  if (lane == 0) red_s[wave] = s2;
  __syncthreads();
  if (tid == 0)
    rs_s = rsqrtf((red_s[0] + red_s[1] + red_s[2] + red_s[3]) * (1.0f / DIM) + EPSV);
  __syncthreads();

  xn_s[tid] = dv * rs_s * gamma[tid] + beta[tid];
  __syncthreads();

  // 64 outputs (32 for a, 32 for b); 4 threads per output split over k.
  const int out = tid >> 2;      // 0..63
  const int part = tid & 3;      // 0..3
  const int which = out >> 5;    // 0 = a, 1 = b
  const int c = out & 31;
  const float* W = which ? Wb : Wa;
  const float4* Wrow = (const float4*)(W + c * DIM);
  const float4* xn4 = (const float4*)xn_s;
  float acc = 0.f;
#pragma unroll
  for (int k = part * 16; k < part * 16 + 16; ++k) {
    float4 w = Wrow[k];
    float4 xx = xn4[k];
    acc += w.x * xx.x + w.y * xx.y + w.z * xx.z + w.w * xx.w;
  }
  psum[tid] = acc;
  __syncthreads();
  if (tid < 64) {
    float v = psum[tid * 4] + psum[tid * 4 + 1] + psum[tid * 4 + 2] + psum[tid * 4 + 3];
    const int wh = tid >> 5, cc = tid & 31;
    if (wh == 0) a_g[i * H + cc] = v;
    else         bT_g[cc * LSEQ + i] = v;
  }
}

// ---------------------------------------------------------------------------
// Kernel 2: t[i, o, d] = sum_c a[i,c] * Wo[o, c*32 + d]
// 2 rows of i per block (192 blocks, 256 threads).
// ---------------------------------------------------------------------------
__global__ __launch_bounds__(256) void t_kernel(
    const float* __restrict__ a_g, const float* __restrict__ Wo,
    float* __restrict__ t_g) {
  const int i0 = blockIdx.x * 2;
  const int tid = threadIdx.x;
  const int o = tid >> 1;   // 0..127
  const int dh = tid & 1;   // which 16-d half
  __shared__ float a_s[2][H];
  if (tid < 64) a_s[tid >> 5][tid & 31] = a_g[(i0 + (tid >> 5)) * H + (tid & 31)];
  __syncthreads();

  float4 acc[2][4];
#pragma unroll
  for (int ii = 0; ii < 2; ++ii)
#pragma unroll
    for (int g = 0; g < 4; ++g) acc[ii][g] = make_float4(0.f, 0.f, 0.f, 0.f);

  const float4* W4 = (const float4*)Wo;
#pragma unroll 4
  for (int c = 0; c < H; ++c) {
    const int base = o * 256 + c * 8 + dh * 4;  // float4 index into Wo row
    const float a0 = a_s[0][c];
    const float a1 = a_s[1][c];
#pragma unroll
    for (int g = 0; g < 4; ++g) {
      float4 w = W4[base + g];
      acc[0][g].x += a0 * w.x; acc[0][g].y += a0 * w.y;
      acc[0][g].z += a0 * w.z; acc[0][g].w += a0 * w.w;
      acc[1][g].x += a1 * w.x; acc[1][g].y += a1 * w.y;
      acc[1][g].z += a1 * w.z; acc[1][g].w += a1 * w.w;
    }
  }

  float4* t4 = (float4*)t_g;
#pragma unroll
  for (int ii = 0; ii < 2; ++ii) {
    const int b4 = (i0 + ii) * (ODIM * H / 4) + o * 8 + dh * 4;
#pragma unroll
    for (int g = 0; g < 4; ++g) t4[b4 + g] = acc[ii][g];
  }
}

// ---------------------------------------------------------------------------
// Kernel 3: z[i, j, o] = sum_d t[i,o,d] * b[j,d] + bo[o]
// Block = (i, j-tile of 128). 256 threads = 16 (o-pair-of-quads) x 16
// (j-groups of 8). Each thread: 8j x 8o register tile (two o-quads: 4*ot and
// 64+4*ot so every LDS read covers a contiguous 256B span -> conflict-free).
// Per d-step: 4 ds_read_b128 feed 64 FMAs (2x better LDS ratio than before).
// ---------------------------------------------------------------------------
#define FMA4(A, S, T)                                        \
  do {                                                       \
    (A).x += (S) * (T).x; (A).y += (S) * (T).y;              \
    (A).z += (S) * (T).z; (A).w += (S) * (T).w;              \
  } while (0)

__global__ __launch_bounds__(256) void z_kernel(
    const float* __restrict__ t_g, const float* __restrict__ bT_g,
    const float* __restrict__ bo, float* __restrict__ z) {
  const int i = blockIdx.x;       // 0..383
  const int jt = blockIdx.y;      // 0..2
  const int tid = threadIdx.x;
  const int ot = tid & 15;        // o-quads 4*ot and 64+4*ot
  const int jg = tid >> 4;        // 0..15 (j-group of 8)

  __shared__ float tt[H][132];    // [d][o], padded row stride 132 floats
  __shared__ float bt[H][128];    // [d][j within tile]

  // Load t[i] (4096 floats) coalesced, transpose into tt.
  const float4* t4 = (const float4*)(t_g + i * (ODIM * H));
#pragma unroll
  for (int k = 0; k < 4; ++k) {
    const int f = tid + k * 256;
    float4 v = t4[f];
    const int o = f >> 3;
    const int d = (f & 7) * 4;
    tt[d][o] = v.x; tt[d + 1][o] = v.y; tt[d + 2][o] = v.z; tt[d + 3][o] = v.w;
  }
  // Load bT rows for this j-tile (32 x 128 floats), float4 coalesced.
#pragma unroll
  for (int k = 0; k < 4; ++k) {
    const int idx4 = tid + k * 256;        // 0..1023 float4 slots
    const int d = idx4 >> 5, c4 = idx4 & 31;
    float4 v = *(const float4*)(bT_g + d * LSEQ + jt * 128 + c4 * 4);
    *(float4*)&bt[d][c4 * 4] = v;
  }
  __syncthreads();

  const float4 bo0 = ((const float4*)bo)[ot];
  const float4 bo1 = ((const float4*)bo)[16 + ot];
  float4 acc0[8], acc1[8];
#pragma unroll
  for (int jj = 0; jj < 8; ++jj) { acc0[jj] = bo0; acc1[jj] = bo1; }

#pragma unroll
  for (int d = 0; d < H; ++d) {
    const float4 tv0 = *(const float4*)&tt[d][ot * 4];
    const float4 tv1 = *(const float4*)&tt[d][64 + ot * 4];
    const float4 b0 = *(const float4*)&bt[d][jg * 8];
    const float4 b1 = *(const float4*)&bt[d][jg * 8 + 4];
    FMA4(acc0[0], b0.x, tv0); FMA4(acc1[0], b0.x, tv1);
    FMA4(acc0[1], b0.y, tv0); FMA4(acc1[1], b0.y, tv1);
    FMA4(acc0[2], b0.z, tv0); FMA4(acc1[2], b0.z, tv1);
    FMA4(acc0[3], b0.w, tv0); FMA4(acc1[3], b0.w, tv1);
    FMA4(acc0[4], b1.x, tv0); FMA4(acc1[4], b1.x, tv1);
    FMA4(acc0[5], b1.y, tv0); FMA4(acc1[5], b1.y, tv1);
    FMA4(acc0[6], b1.z, tv0); FMA4(acc1[6], b1.z, tv1);
    FMA4(acc0[7], b1.w, tv0); FMA4(acc1[7], b1.w, tv1);
  }

  float4* z4 = (float4*)z;
  const int jbase = jt * 128 + jg * 8;
#pragma unroll
  for (int jj = 0; jj < 8; ++jj) {
    const size_t row = (size_t)(i * LSEQ + jbase + jj) * 32;
    z4[row + ot] = acc0[jj];
    z4[row + 16 + ot] = acc1[jj];
  }
}

// ---------------------------------------------------------------------------
extern "C" void kernel_launch(void* const* d_in, const int* in_sizes, int n_in,
                              void* d_out, int out_size, void* d_ws, size_t ws_size,
                              hipStream_t stream) {
  const float* x     = (const float*)d_in[0];
  const float* gamma = (const float*)d_in[1];
  const float* beta  = (const float*)d_in[2];
  const float* Wa    = (const float*)d_in[3];
  const float* Wb    = (const float*)d_in[4];
  const float* Wo    = (const float*)d_in[5];
  const float* bo    = (const float*)d_in[6];
  float* z = (float*)d_out;

  float* ws   = (float*)d_ws;
  float* a_g  = ws;                       // 384*32
  float* bT_g = ws + LSEQ * H;            // 32*384
  float* t_g  = ws + 2 * LSEQ * H;        // 384*128*32 floats

  hipLaunchKernelGGL(ln_ab_kernel, dim3(LSEQ), dim3(256), 0, stream,
                     x, gamma, beta, Wa, Wb, a_g, bT_g);
  hipLaunchKernelGGL(t_kernel, dim3(LSEQ / 2), dim3(256), 0, stream,
                     a_g, Wo, t_g);
  hipLaunchKernelGGL(z_kernel, dim3(LSEQ, LSEQ / 128), dim3(256), 0, stream,
                     t_g, bT_g, bo, z);
}

// Round 3
// 127.245 us; speedup vs baseline: 1.0346x; 1.0346x over previous
//
#include <hip/hip_runtime.h>

#define LSEQ 384
#define DIM 256
#define H 32
#define ODIM 128
#define EPSV 1e-5f

// ---------------------------------------------------------------------------
// Kernel 1 (fused): LayerNorm + a/b projections + t[i,o,d] = sum_c a[i,c]*Wo[o,c*32+d]
// One block per 2 rows of i (192 blocks, 256 threads).
// a never leaves LDS; bT goes to global for z's b-tiles; t[i][o][d] to global.
// ---------------------------------------------------------------------------
__global__ __launch_bounds__(256) void ln_ab_t_kernel(
    const float* __restrict__ x, const float* __restrict__ gamma,
    const float* __restrict__ beta, const float* __restrict__ Wa,
    const float* __restrict__ Wb, const float* __restrict__ Wo,
    float* __restrict__ bT_g, float* __restrict__ t_g) {
  const int i0 = blockIdx.x * 2;
  const int tid = threadIdx.x;
  __shared__ float xn_s[2][DIM];
  __shared__ float psum[2][256];
  __shared__ float red_s[2][4];
  __shared__ float mu_s[2], rs_s[2];
  __shared__ float a_s[2][H];

  const float xv0 = x[i0 * DIM + tid];
  const float xv1 = x[(i0 + 1) * DIM + tid];
  const int wave = tid >> 6, lane = tid & 63;

  // means (both rows through one shuffle ladder)
  float s0 = xv0, s1 = xv1;
#pragma unroll
  for (int off = 32; off > 0; off >>= 1) {
    s0 += __shfl_down(s0, off, 64);
    s1 += __shfl_down(s1, off, 64);
  }
  if (lane == 0) { red_s[0][wave] = s0; red_s[1][wave] = s1; }
  __syncthreads();
  if (tid < 2)
    mu_s[tid] = (red_s[tid][0] + red_s[tid][1] + red_s[tid][2] + red_s[tid][3]) * (1.0f / DIM);
  __syncthreads();
  const float dv0 = xv0 - mu_s[0];
  const float dv1 = xv1 - mu_s[1];

  // variances
  float q0 = dv0 * dv0, q1 = dv1 * dv1;
#pragma unroll
  for (int off = 32; off > 0; off >>= 1) {
    q0 += __shfl_down(q0, off, 64);
    q1 += __shfl_down(q1, off, 64);
  }
  if (lane == 0) { red_s[0][wave] = q0; red_s[1][wave] = q1; }
  __syncthreads();
  if (tid < 2)
    rs_s[tid] = rsqrtf((red_s[tid][0] + red_s[tid][1] + red_s[tid][2] + red_s[tid][3]) * (1.0f / DIM) + EPSV);
  __syncthreads();

  const float g = gamma[tid], bb = beta[tid];
  xn_s[0][tid] = dv0 * rs_s[0] * g + bb;
  xn_s[1][tid] = dv1 * rs_s[1] * g + bb;
  __syncthreads();

  // projections: 64 outputs (32 a, 32 b) x 4 k-parts; both rows per thread.
  {
    const int out = tid >> 2;     // 0..63
    const int part = tid & 3;     // 0..3
    const int which = out >> 5;   // 0 = a, 1 = b
    const int c = out & 31;
    const float* W = which ? Wb : Wa;
    const float4* Wrow = (const float4*)(W + c * DIM);
    const float4* xn40 = (const float4*)&xn_s[0][0];
    const float4* xn41 = (const float4*)&xn_s[1][0];
    float acc0 = 0.f, acc1 = 0.f;
#pragma unroll
    for (int k = part * 16; k < part * 16 + 16; ++k) {
      const float4 w = Wrow[k];
      const float4 x0 = xn40[k];
      const float4 x1 = xn41[k];
      acc0 += w.x * x0.x + w.y * x0.y + w.z * x0.z + w.w * x0.w;
      acc1 += w.x * x1.x + w.y * x1.y + w.z * x1.z + w.w * x1.w;
    }
    psum[0][tid] = acc0;
    psum[1][tid] = acc1;
  }
  __syncthreads();
  if (tid < 128) {
    const int row = tid >> 6;     // which i
    const int out = tid & 63;
    const float v = psum[row][out * 4] + psum[row][out * 4 + 1] +
                    psum[row][out * 4 + 2] + psum[row][out * 4 + 3];
    const int wh = out >> 5, cc = out & 31;
    if (wh == 0) a_s[row][cc] = v;
    else         bT_g[cc * LSEQ + i0 + row] = v;
  }
  __syncthreads();

  // t stage: thread = (o, d-half); both rows.
  const int o = tid >> 1;   // 0..127
  const int dh = tid & 1;   // which 16-d half
  float4 acc[2][4];
#pragma unroll
  for (int ii = 0; ii < 2; ++ii)
#pragma unroll
    for (int gg = 0; gg < 4; ++gg) acc[ii][gg] = make_float4(0.f, 0.f, 0.f, 0.f);

  const float4* W4 = (const float4*)Wo;
#pragma unroll 4
  for (int c = 0; c < H; ++c) {
    const int base = o * 256 + c * 8 + dh * 4;
    const float a0 = a_s[0][c];
    const float a1 = a_s[1][c];
#pragma unroll
    for (int gg = 0; gg < 4; ++gg) {
      const float4 w = W4[base + gg];
      acc[0][gg].x += a0 * w.x; acc[0][gg].y += a0 * w.y;
      acc[0][gg].z += a0 * w.z; acc[0][gg].w += a0 * w.w;
      acc[1][gg].x += a1 * w.x; acc[1][gg].y += a1 * w.y;
      acc[1][gg].z += a1 * w.z; acc[1][gg].w += a1 * w.w;
    }
  }

  float4* t4 = (float4*)t_g;
#pragma unroll
  for (int ii = 0; ii < 2; ++ii) {
    const int b4 = (i0 + ii) * (ODIM * H / 4) + o * 8 + dh * 4;
#pragma unroll
    for (int gg = 0; gg < 4; ++gg) t4[b4 + gg] = acc[ii][gg];
  }
}

// ---------------------------------------------------------------------------
// Kernel 2: z[i, j, o] = sum_d t[i,o,d] * b[j,d] + bo[o]
// Block = (i, j-tile of 128). 256 threads = 16 (o-pair-of-quads) x 16
// (j-groups of 8). Thread: 8j x 8o register tile; 4 ds_read_b128 per d-step
// feed 64 FMAs; conflict-free LDS; float4 coalesced stores.
// ---------------------------------------------------------------------------
#define FMA4(A, S, T)                                        \
  do {                                                       \
    (A).x += (S) * (T).x; (A).y += (S) * (T).y;              \
    (A).z += (S) * (T).z; (A).w += (S) * (T).w;              \
  } while (0)

__global__ __launch_bounds__(256) void z_kernel(
    const float* __restrict__ t_g, const float* __restrict__ bT_g,
    const float* __restrict__ bo, float* __restrict__ z) {
  const int i = blockIdx.x;       // 0..383
  const int jt = blockIdx.y;      // 0..2
  const int tid = threadIdx.x;
  const int ot = tid & 15;        // o-quads 4*ot and 64+4*ot
  const int jg = tid >> 4;        // 0..15 (j-group of 8)

  __shared__ float tt[H][132];    // [d][o], padded row stride
  __shared__ float bt[H][128];    // [d][j within tile]

  const float4* t4 = (const float4*)(t_g + i * (ODIM * H));
#pragma unroll
  for (int k = 0; k < 4; ++k) {
    const int f = tid + k * 256;
    const float4 v = t4[f];
    const int o = f >> 3;
    const int d = (f & 7) * 4;
    tt[d][o] = v.x; tt[d + 1][o] = v.y; tt[d + 2][o] = v.z; tt[d + 3][o] = v.w;
  }
#pragma unroll
  for (int k = 0; k < 4; ++k) {
    const int idx4 = tid + k * 256;
    const int d = idx4 >> 5, c4 = idx4 & 31;
    const float4 v = *(const float4*)(bT_g + d * LSEQ + jt * 128 + c4 * 4);
    *(float4*)&bt[d][c4 * 4] = v;
  }
  __syncthreads();

  const float4 bo0 = ((const float4*)bo)[ot];
  const float4 bo1 = ((const float4*)bo)[16 + ot];
  float4 acc0[8], acc1[8];
#pragma unroll
  for (int jj = 0; jj < 8; ++jj) { acc0[jj] = bo0; acc1[jj] = bo1; }

#pragma unroll
  for (int d = 0; d < H; ++d) {
    const float4 tv0 = *(const float4*)&tt[d][ot * 4];
    const float4 tv1 = *(const float4*)&tt[d][64 + ot * 4];
    const float4 b0 = *(const float4*)&bt[d][jg * 8];
    const float4 b1 = *(const float4*)&bt[d][jg * 8 + 4];
    FMA4(acc0[0], b0.x, tv0); FMA4(acc1[0], b0.x, tv1);
    FMA4(acc0[1], b0.y, tv0); FMA4(acc1[1], b0.y, tv1);
    FMA4(acc0[2], b0.z, tv0); FMA4(acc1[2], b0.z, tv1);
    FMA4(acc0[3], b0.w, tv0); FMA4(acc1[3], b0.w, tv1);
    FMA4(acc0[4], b1.x, tv0); FMA4(acc1[4], b1.x, tv1);
    FMA4(acc0[5], b1.y, tv0); FMA4(acc1[5], b1.y, tv1);
    FMA4(acc0[6], b1.z, tv0); FMA4(acc1[6], b1.z, tv1);
    FMA4(acc0[7], b1.w, tv0); FMA4(acc1[7], b1.w, tv1);
  }

  float4* z4 = (float4*)z;
  const int jbase = jt * 128 + jg * 8;
#pragma unroll
  for (int jj = 0; jj < 8; ++jj) {
    const size_t row = (size_t)(i * LSEQ + jbase + jj) * 32;
    z4[row + ot] = acc0[jj];
    z4[row + 16 + ot] = acc1[jj];
  }
}

// ---------------------------------------------------------------------------
extern "C" void kernel_launch(void* const* d_in, const int* in_sizes, int n_in,
                              void* d_out, int out_size, void* d_ws, size_t ws_size,
                              hipStream_t stream) {
  const float* x     = (const float*)d_in[0];
  const float* gamma = (const float*)d_in[1];
  const float* beta  = (const float*)d_in[2];
  const float* Wa    = (const float*)d_in[3];
  const float* Wb    = (const float*)d_in[4];
  const float* Wo    = (const float*)d_in[5];
  const float* bo    = (const float*)d_in[6];
  float* z = (float*)d_out;

  float* ws   = (float*)d_ws;
  float* bT_g = ws;                       // 32*384
  float* t_g  = ws + LSEQ * H;            // 384*128*32 floats

  hipLaunchKernelGGL(ln_ab_t_kernel, dim3(LSEQ / 2), dim3(256), 0, stream,
                     x, gamma, beta, Wa, Wb, Wo, bT_g, t_g);
  hipLaunchKernelGGL(z_kernel, dim3(LSEQ, LSEQ / 128), dim3(256), 0, stream,
                     t_g, bT_g, bo, z);
}